// Round 1
// baseline (220.799 us; speedup 1.0000x reference)
//
#include <hip/hip_runtime.h>

#define IN_F 128
#define OUT_F 64

// -------- kernel 1: support = x @ W  ([N,128] x [128,64]) --------
// Block = 256 threads, 8 rows per block. W staged in LDS (32 KB),
// 8 x-rows staged in LDS (4 KB). Thread (g = tid>>6, c = tid&63)
// computes rows {g, g+4} of the block's 8 rows, sharing each W read.
__global__ __launch_bounds__(256) void gcn_matmul(
    const float* __restrict__ x, const float* __restrict__ w,
    float* __restrict__ support, int n_nodes)
{
    __shared__ float Wl[IN_F * OUT_F];   // 32 KB, Wl[k*64+c]
    __shared__ float xs[8][IN_F];        // 4 KB

    const int tid = threadIdx.x;
    const int row0 = blockIdx.x * 8;

    #pragma unroll
    for (int i = tid; i < IN_F * OUT_F; i += 256)
        Wl[i] = w[i];

    #pragma unroll
    for (int i = tid; i < 8 * IN_F; i += 256) {
        int r = i >> 7, k = i & (IN_F - 1);
        int gr = row0 + r;
        xs[r][k] = (gr < n_nodes) ? x[gr * IN_F + k] : 0.0f;
    }
    __syncthreads();

    const int c = tid & 63;
    const int g = tid >> 6;          // 0..3
    float acc0 = 0.0f, acc1 = 0.0f;

    #pragma unroll 8
    for (int k = 0; k < IN_F; ++k) {
        float wv = Wl[k * OUT_F + c];        // lanes 0..63 -> 2-way bank alias (free)
        acc0 = fmaf(xs[g][k], wv, acc0);     // broadcast read
        acc1 = fmaf(xs[g + 4][k], wv, acc1); // broadcast read
    }

    int r0 = row0 + g, r1 = row0 + g + 4;
    if (r0 < n_nodes) support[r0 * OUT_F + c] = acc0;
    if (r1 < n_nodes) support[r1 * OUT_F + c] = acc1;
}

// -------- kernel 2: out[n][c] = bias[c] --------
__global__ __launch_bounds__(256) void gcn_bias_init(
    const float* __restrict__ bias, float* __restrict__ out, int total)
{
    int i = blockIdx.x * 256 + threadIdx.x;
    if (i < total) out[i] = bias[i & (OUT_F - 1)];
}

// -------- kernel 3: atomic scatter of edge messages --------
// One wave per edge; lane c handles column c.
__global__ __launch_bounds__(256) void gcn_scatter(
    const float* __restrict__ support,
    const int* __restrict__ esrc, const int* __restrict__ edst,
    const float* __restrict__ ewgt,
    float* __restrict__ out, int n_edges)
{
    int gid = blockIdx.x * 256 + threadIdx.x;
    int e = gid >> 6;
    if (e >= n_edges) return;
    int lane = gid & 63;

    int s = esrc[e];
    int d = edst[e];
    float w = ewgt[e];

    float v = w * support[s * OUT_F + lane];
    atomicAdd(&out[d * OUT_F + lane], v);
}

extern "C" void kernel_launch(void* const* d_in, const int* in_sizes, int n_in,
                              void* d_out, int out_size, void* d_ws, size_t ws_size,
                              hipStream_t stream) {
    const float* x    = (const float*)d_in[0];
    const int*   esrc = (const int*)d_in[1];
    const int*   edst = (const int*)d_in[2];
    const float* ewgt = (const float*)d_in[3];
    const float* w    = (const float*)d_in[4];
    const float* bias = (const float*)d_in[5];
    float* out = (float*)d_out;

    const int n_nodes = in_sizes[0] / IN_F;
    const int n_edges = in_sizes[1];

    float* support = (float*)d_ws;   // n_nodes * OUT_F floats = 12.8 MB

    // support = x @ W
    int mm_blocks = (n_nodes + 7) / 8;
    gcn_matmul<<<mm_blocks, 256, 0, stream>>>(x, w, support, n_nodes);

    // out = bias (broadcast)
    int total = n_nodes * OUT_F;
    gcn_bias_init<<<(total + 255) / 256, 256, 0, stream>>>(bias, out, total);

    // out[dst] += w_e * support[src]
    long long threads = (long long)n_edges * 64;
    int sc_blocks = (int)((threads + 255) / 256);
    gcn_scatter<<<sc_blocks, 256, 0, stream>>>(support, esrc, edst, ewgt, out, n_edges);
}

// Round 2
// 165.581 us; speedup vs baseline: 1.3335x; 1.3335x over previous
//
#include <hip/hip_runtime.h>

#define IN_F 128
#define OUT_F 64

// -------- kernel 1: support = x @ W  ([N,128] x [128,64]) --------
__global__ __launch_bounds__(256) void gcn_matmul(
    const float* __restrict__ x, const float* __restrict__ w,
    float* __restrict__ support, int n_nodes)
{
    __shared__ float Wl[IN_F * OUT_F];   // 32 KB, Wl[k*64+c]
    __shared__ float xs[8][IN_F];        // 4 KB

    const int tid = threadIdx.x;
    const int row0 = blockIdx.x * 8;

    #pragma unroll
    for (int i = tid; i < IN_F * OUT_F; i += 256)
        Wl[i] = w[i];

    #pragma unroll
    for (int i = tid; i < 8 * IN_F; i += 256) {
        int r = i >> 7, k = i & (IN_F - 1);
        int gr = row0 + r;
        xs[r][k] = (gr < n_nodes) ? x[gr * IN_F + k] : 0.0f;
    }
    __syncthreads();

    const int c = tid & 63;
    const int g = tid >> 6;
    float acc0 = 0.0f, acc1 = 0.0f;

    #pragma unroll 8
    for (int k = 0; k < IN_F; ++k) {
        float wv = Wl[k * OUT_F + c];
        acc0 = fmaf(xs[g][k], wv, acc0);
        acc1 = fmaf(xs[g + 4][k], wv, acc1);
    }

    int r0 = row0 + g, r1 = row0 + g + 4;
    if (r0 < n_nodes) support[r0 * OUT_F + c] = acc0;
    if (r1 < n_nodes) support[r1 * OUT_F + c] = acc1;
}

// -------- CSR build --------
__global__ __launch_bounds__(256) void gcn_hist(
    const int* __restrict__ edst, int* __restrict__ counts, int n_edges)
{
    int e = blockIdx.x * 256 + threadIdx.x;
    if (e < n_edges) atomicAdd(&counts[edst[e]], 1);
}

__global__ __launch_bounds__(256) void gcn_scan1(
    const int* __restrict__ counts, int* __restrict__ offs,
    int* __restrict__ partial, int n)
{
    __shared__ int sm[256];
    int i = blockIdx.x * 256 + threadIdx.x;
    int v = (i < n) ? counts[i] : 0;
    sm[threadIdx.x] = v;
    __syncthreads();
    #pragma unroll
    for (int off = 1; off < 256; off <<= 1) {
        int t = (threadIdx.x >= off) ? sm[threadIdx.x - off] : 0;
        __syncthreads();
        sm[threadIdx.x] += t;
        __syncthreads();
    }
    if (i < n) offs[i] = sm[threadIdx.x] - v;          // exclusive within block
    if (threadIdx.x == 255) partial[blockIdx.x] = sm[255];
}

__global__ __launch_bounds__(256) void gcn_scan2(int* partial, int nb)
{
    __shared__ int sm[256];
    int v = (threadIdx.x < nb) ? partial[threadIdx.x] : 0;
    sm[threadIdx.x] = v;
    __syncthreads();
    #pragma unroll
    for (int off = 1; off < 256; off <<= 1) {
        int t = (threadIdx.x >= off) ? sm[threadIdx.x - off] : 0;
        __syncthreads();
        sm[threadIdx.x] += t;
        __syncthreads();
    }
    if (threadIdx.x < nb) partial[threadIdx.x] = sm[threadIdx.x] - v;  // exclusive
}

__global__ __launch_bounds__(256) void gcn_scan3(
    int* __restrict__ offs, const int* __restrict__ partial,
    int* __restrict__ cursor, int n)
{
    int i = blockIdx.x * 256 + threadIdx.x;
    if (i < n) {
        int o = offs[i] + partial[blockIdx.x];
        offs[i] = o;
        cursor[i] = o;
    }
}

__global__ __launch_bounds__(256) void gcn_reorder(
    const int* __restrict__ esrc, const int* __restrict__ edst,
    const float* __restrict__ ewgt, int* __restrict__ cursor,
    int2* __restrict__ pairs, int n_edges)
{
    int e = blockIdx.x * 256 + threadIdx.x;
    if (e >= n_edges) return;
    int d = edst[e];
    int pos = atomicAdd(&cursor[d], 1);
    pairs[pos] = make_int2(esrc[e], __float_as_int(ewgt[e]));
}

// -------- gather: one wave per node, zero float atomics --------
__global__ __launch_bounds__(256) void gcn_gather(
    const float* __restrict__ support, const int* __restrict__ offs,
    const int* __restrict__ ends, const int2* __restrict__ pairs,
    const float* __restrict__ bias, float* __restrict__ out, int n_nodes)
{
    int wid = (blockIdx.x * 256 + threadIdx.x) >> 6;
    if (wid >= n_nodes) return;
    int lane = threadIdx.x & 63;

    int start = offs[wid];
    int end   = ends[wid];     // cursor after reorder == offs + deg
    float acc = 0.0f;

    for (int base = start; base < end; base += 64) {
        int nb = end - base; if (nb > 64) nb = 64;
        int2 pr = make_int2(0, 0);
        if (base + lane < end) pr = pairs[base + lane];   // one coalesced load
        int   my_s = pr.x;
        float my_w = __int_as_float(pr.y);

        int d = 0;
        for (; d + 4 <= nb; d += 4) {
            int   s0 = __shfl(my_s, d),     s1 = __shfl(my_s, d + 1);
            int   s2 = __shfl(my_s, d + 2), s3 = __shfl(my_s, d + 3);
            float w0 = __shfl(my_w, d),     w1 = __shfl(my_w, d + 1);
            float w2 = __shfl(my_w, d + 2), w3 = __shfl(my_w, d + 3);
            float v0 = support[s0 * OUT_F + lane];
            float v1 = support[s1 * OUT_F + lane];
            float v2 = support[s2 * OUT_F + lane];
            float v3 = support[s3 * OUT_F + lane];
            acc = fmaf(w0, v0, acc);
            acc = fmaf(w1, v1, acc);
            acc = fmaf(w2, v2, acc);
            acc = fmaf(w3, v3, acc);
        }
        for (; d < nb; ++d) {
            int   s = __shfl(my_s, d);
            float w = __shfl(my_w, d);
            acc = fmaf(w, support[s * OUT_F + lane], acc);
        }
    }
    out[wid * OUT_F + lane] = acc + bias[lane];
}

// -------- fallback kernels (atomic scatter) if ws too small --------
__global__ __launch_bounds__(256) void gcn_bias_init(
    const float* __restrict__ bias, float* __restrict__ out, int total)
{
    int i = blockIdx.x * 256 + threadIdx.x;
    if (i < total) out[i] = bias[i & (OUT_F - 1)];
}

__global__ __launch_bounds__(256) void gcn_scatter(
    const float* __restrict__ support,
    const int* __restrict__ esrc, const int* __restrict__ edst,
    const float* __restrict__ ewgt,
    float* __restrict__ out, int n_edges)
{
    int gid = blockIdx.x * 256 + threadIdx.x;
    int e = gid >> 6;
    if (e >= n_edges) return;
    int lane = gid & 63;
    float v = ewgt[e] * support[esrc[e] * OUT_F + lane];
    atomicAdd(&out[edst[e] * OUT_F + lane], v);
}

extern "C" void kernel_launch(void* const* d_in, const int* in_sizes, int n_in,
                              void* d_out, int out_size, void* d_ws, size_t ws_size,
                              hipStream_t stream) {
    const float* x    = (const float*)d_in[0];
    const int*   esrc = (const int*)d_in[1];
    const int*   edst = (const int*)d_in[2];
    const float* ewgt = (const float*)d_in[3];
    const float* w    = (const float*)d_in[4];
    const float* bias = (const float*)d_in[5];
    float* out = (float*)d_out;

    const int n_nodes = in_sizes[0] / IN_F;
    const int n_edges = in_sizes[1];

    // workspace carve-up (all 16B-aligned)
    char* ws = (char*)d_ws;
    size_t sup_bytes    = (size_t)n_nodes * OUT_F * sizeof(float);
    size_t cnt_bytes    = ((size_t)n_nodes * sizeof(int) + 15) & ~15ull;
    size_t part_bytes   = 256 * sizeof(int);
    size_t pairs_bytes  = (size_t)n_edges * sizeof(int2);

    float* support = (float*)ws;                       ws += sup_bytes;
    int*   counts  = (int*)ws;                         ws += cnt_bytes;
    int*   offs    = (int*)ws;                         ws += cnt_bytes;
    int*   cursor  = (int*)ws;                         ws += cnt_bytes;
    int*   partial = (int*)ws;                         ws += part_bytes;
    int2*  pairs   = (int2*)ws;                        ws += pairs_bytes;

    size_t need = (size_t)(ws - (char*)d_ws);

    // support = x @ W
    int mm_blocks = (n_nodes + 7) / 8;
    gcn_matmul<<<mm_blocks, 256, 0, stream>>>(x, w, support, n_nodes);

    int eb = (n_edges + 255) / 256;
    int nb = (n_nodes + 255) / 256;

    if (need <= ws_size && nb <= 256) {
        // CSR build + gather path
        hipMemsetAsync(counts, 0, (size_t)n_nodes * sizeof(int), stream);
        gcn_hist<<<eb, 256, 0, stream>>>(edst, counts, n_edges);
        gcn_scan1<<<nb, 256, 0, stream>>>(counts, offs, partial, n_nodes);
        gcn_scan2<<<1, 256, 0, stream>>>(partial, nb);
        gcn_scan3<<<nb, 256, 0, stream>>>(offs, partial, cursor, n_nodes);
        gcn_reorder<<<eb, 256, 0, stream>>>(esrc, edst, ewgt, cursor, pairs, n_edges);
        int gb = (n_nodes + 3) / 4;   // 4 waves per block, 1 node per wave
        gcn_gather<<<gb, 256, 0, stream>>>(support, offs, cursor, pairs, bias, out, n_nodes);
    } else {
        // fallback: atomic scatter
        int total = n_nodes * OUT_F;
        gcn_bias_init<<<(total + 255) / 256, 256, 0, stream>>>(bias, out, total);
        long long threads = (long long)n_edges * 64;
        int sc_blocks = (int)((threads + 255) / 256);
        gcn_scatter<<<sc_blocks, 256, 0, stream>>>(support, esrc, edst, ewgt, out, n_edges);
    }
}